// Round 2
// baseline (4626.680 us; speedup 1.0000x reference)
//
#include <hip/hip_runtime.h>
#include <math.h>

#define TB 256
#define BM 64
#define BN 64
#define BK 16

// Implicit-GEMM conv: Out[z][m][n] = sum_k A[m][k] * B(k,n) + bias[m]
// MODE 0: zero-pad im2col   MODE 1: reflect-pad im2col   MODE 2: deform bilinear sample * sigmoid(mask)
template<int CIN,int KH,int KW,int STR,int PAD,int H,int W,int HO,int WO,int MODE>
__global__ __launch_bounds__(TB) void conv_gemm(
    const float* __restrict__ A,      // [M x Ktot] weights (OIHW flat)
    const float* __restrict__ X,      // [Z][CIN][H][W]
    const float* __restrict__ OM,     // [Z][3*Kk][HO][WO] (deform only)
    const float* __restrict__ bias,   // [M]
    float* __restrict__ Out,          // [Z][M][HO*WO]
    int M)
{
    constexpr int Kk   = KH*KW;
    constexpr int Ktot = CIN*Kk;
    constexpr int HWc  = H*W;
    constexpr int HOWO = HO*WO;

    const int z = blockIdx.z;
    const float* __restrict__ Xb  = X + (size_t)z * CIN * HWc;
    const float* __restrict__ OMb = (MODE == 2) ? (OM + (size_t)z * 3 * Kk * HOWO) : nullptr;
    float* __restrict__ Outb = Out + (size_t)z * (size_t)M * HOWO;

    const int n0  = blockIdx.x * BN;
    const int m0  = blockIdx.y * BM;
    const int tid = threadIdx.x;
    const int tx  = tid & 15;   // n-group
    const int ty  = tid >> 4;   // m-group

    __shared__ float As[BK][BM];
    __shared__ float Bs[BK][BN];

    float acc[4][4] = {};

    for (int k0 = 0; k0 < Ktot; k0 += BK) {
        // ---- stage A tile: As[k][m] = A[m0+m][k0+k]
        {
            int m  = tid >> 2;
            int k4 = (tid & 3) * 4;
            int gm = m0 + m;
            const float* Arow = A + (size_t)gm * Ktot + (size_t)(k0 + k4);
#pragma unroll
            for (int j = 0; j < 4; ++j) {
                int gk = k0 + k4 + j;
                float v = (gm < M && gk < Ktot) ? Arow[j] : 0.f;
                As[k4 + j][m] = v;
            }
        }
        // ---- stage B tile: Bs[k][n] = sampled input
#pragma unroll
        for (int i = 0; i < (BN * BK) / TB; ++i) {
            int flat = tid + i * TB;
            int n = flat & (BN - 1);
            int k = flat >> 6;
            int gk = k0 + k;
            float v = 0.f;
            if (gk < Ktot) {
                int gn = n0 + n;
                int ci = gk / Kk;
                int r  = gk % Kk;
                int ho = gn / WO;
                int wo = gn % WO;
                int ky = r / KW, kx = r % KW;
                if constexpr (MODE == 0) {
                    int iy = ho * STR - PAD + ky;
                    int ix = wo * STR - PAD + kx;
                    if (iy >= 0 && iy < H && ix >= 0 && ix < W)
                        v = Xb[(size_t)ci * HWc + iy * W + ix];
                } else if constexpr (MODE == 1) {
                    int iy = ho - PAD + ky; iy = iy < 0 ? -iy : (iy >= H ? 2 * H - 2 - iy : iy);
                    int ix = wo - PAD + kx; ix = ix < 0 ? -ix : (ix >= W ? 2 * W - 2 - ix : ix);
                    v = Xb[(size_t)ci * HWc + iy * W + ix];
                } else {
                    // DCNv2 offset layout: off = concat(o1,o2).reshape(K,2,..)
                    // => offy = om channel 2r, offx = om channel 2r+1, mask = 2K + r
                    const float* img = Xb + (size_t)ci * HWc;
                    float offy = OMb[(size_t)(2 * r) * HOWO + gn];
                    float offx = OMb[(size_t)(2 * r + 1) * HOWO + gn];
                    float ml   = OMb[(size_t)(2 * Kk + r) * HOWO + gn];
                    float mask = 1.f / (1.f + expf(-ml));
                    float ys = (float)(ho * STR - PAD + ky) + offy;
                    float xs = (float)(wo * STR - PAD + kx) + offx;
                    float y0f = floorf(ys), x0f = floorf(xs);
                    float dy = ys - y0f, dx = xs - x0f;
                    int y0 = (int)y0f, x0 = (int)x0f;
                    auto corner = [&](int yy, int xx) -> float {
                        if (yy < 0 || yy >= H || xx < 0 || xx >= W) return 0.f;
                        return img[yy * W + xx];
                    };
                    float v00 = corner(y0,     x0);
                    float v01 = corner(y0,     x0 + 1);
                    float v10 = corner(y0 + 1, x0);
                    float v11 = corner(y0 + 1, x0 + 1);
                    v = (v00 * (1.f - dy) * (1.f - dx) + v01 * (1.f - dy) * dx +
                         v10 * dy * (1.f - dx) + v11 * dy * dx) * mask;
                }
            }
            Bs[k][n] = v;
        }
        __syncthreads();

#pragma unroll
        for (int kk = 0; kk < BK; ++kk) {
            float4 a4 = *(const float4*)&As[kk][ty * 4];
            float4 b4 = *(const float4*)&Bs[kk][tx * 4];
            float av[4] = {a4.x, a4.y, a4.z, a4.w};
            float bv[4] = {b4.x, b4.y, b4.z, b4.w};
#pragma unroll
            for (int i = 0; i < 4; ++i)
#pragma unroll
                for (int j = 0; j < 4; ++j)
                    acc[i][j] = fmaf(av[i], bv[j], acc[i][j]);
        }
        __syncthreads();
    }

    // epilogue: add bias, store (N is always a multiple of 64; guard only m)
#pragma unroll
    for (int i = 0; i < 4; ++i) {
        int m = m0 + ty * 4 + i;
        if (m < M) {
            float bia = bias[m];
            float4 o;
            o.x = acc[i][0] + bia; o.y = acc[i][1] + bia;
            o.z = acc[i][2] + bia; o.w = acc[i][3] + bia;
            *(float4*)&Outb[(size_t)m * HOWO + n0 + tx * 4] = o;
        }
    }
}

// Instance norm over HW per (b,c) block; optional ReLU, dual-write, add-into-out.
template<bool RELU, bool DUAL, bool ADDIN>
__global__ __launch_bounds__(TB) void instnorm_k(
    const float* __restrict__ in, float* __restrict__ out,
    float* __restrict__ out2, int HW)
{
    const int bc = blockIdx.x;
    const float* p = in + (size_t)bc * HW;
    float s = 0.f, ss = 0.f;
    for (int i = threadIdx.x; i < HW; i += TB) { float v = p[i]; s += v; ss += v * v; }
    __shared__ float rs[TB], rq[TB];
    rs[threadIdx.x] = s; rq[threadIdx.x] = ss;
    __syncthreads();
    for (int o = TB / 2; o > 0; o >>= 1) {
        if (threadIdx.x < o) { rs[threadIdx.x] += rs[threadIdx.x + o]; rq[threadIdx.x] += rq[threadIdx.x + o]; }
        __syncthreads();
    }
    float mean = rs[0] / (float)HW;
    float var  = rq[0] / (float)HW - mean * mean;
    float inv  = rsqrtf(var + 1e-5f);
    float* q  = out + (size_t)bc * HW;
    float* q2 = DUAL ? (out2 + (size_t)bc * HW) : nullptr;
    for (int i = threadIdx.x; i < HW; i += TB) {
        float v = (p[i] - mean) * inv;
        if (RELU) v = fmaxf(v, 0.f);
        if (ADDIN) {
            q[i] = q[i] + v;
        } else {
            q[i] = v;
            if (DUAL) q2[i] = v;
        }
    }
}

extern "C" void kernel_launch(void* const* d_in, const int* in_sizes, int n_in,
                              void* d_out, int out_size, void* d_ws, size_t ws_size,
                              hipStream_t stream)
{
    const float* x      = (const float*)d_in[0];
    const float* w_off1 = (const float*)d_in[1];
    const float* b_off1 = (const float*)d_in[2];
    const float* w1     = (const float*)d_in[3];
    const float* b1     = (const float*)d_in[4];
    const float* w_off2 = (const float*)d_in[5];
    const float* b_off2 = (const float*)d_in[6];
    const float* w2     = (const float*)d_in[7];
    const float* b2     = (const float*)d_in[8];
    const float* w_off3 = (const float*)d_in[9];
    const float* b_off3 = (const float*)d_in[10];
    const float* w3     = (const float*)d_in[11];
    const float* b3     = (const float*)d_in[12];
    const float* rwa[2] = {(const float*)d_in[13], (const float*)d_in[17]};
    const float* rba[2] = {(const float*)d_in[14], (const float*)d_in[18]};
    const float* rwb[2] = {(const float*)d_in[15], (const float*)d_in[19]};
    const float* rbb[2] = {(const float*)d_in[16], (const float*)d_in[20]};

    float* out   = (float*)d_out;
    float* h_out = out;                         // [16,256,32,32]
    float* skip2 = out + 4194304;               // [16,128,64,64]
    float* skip3 = out + 4194304 + 8388608;     // [16,256,32,32]

    // workspace layout (floats). om1 (stage-1 only, per-batch) aliases the later pool.
    float* wsf = (float*)d_ws;
    float* h1  = wsf;                       // 16,777,216  [16,64,128,128]
    float* pool = h1 + 16777216;
    float* om2 = pool;                      // 3,145,728   [16,48,64,64]
    float* om3 = om2 + 3145728;             //   786,432   [16,48,32,32]
    float* y1  = om3 + 786432;              // 4,194,304   [16,256,32,32]
    float* y2  = y1 + 4194304;              // 4,194,304
    float* om1 = pool;                      // 2,408,448 per batch (aliases om2.., dead before stage 2)

    // ---- Stage 1: 7x7 s1 p3, Cin=3 -> 64ch @128x128 (per-batch to bound om1)
    for (int b = 0; b < 16; ++b) {
        const float* xb = x + (size_t)b * 3 * 128 * 128;
        conv_gemm<3,7,7,1,3,128,128,128,128,0><<<dim3(256, 3, 1), TB, 0, stream>>>(
            w_off1, xb, nullptr, b_off1, om1, 147);
        conv_gemm<3,7,7,1,3,128,128,128,128,2><<<dim3(256, 1, 1), TB, 0, stream>>>(
            w1, xb, om1, b1, h1 + (size_t)b * 64 * 16384, 64);
    }
    instnorm_k<true,false,false><<<16 * 64, TB, 0, stream>>>(h1, h1, nullptr, 16384);

    // ---- Stage 2: 4x4 s2 p1, 64 -> 128ch @64x64
    conv_gemm<64,4,4,2,1,128,128,64,64,0><<<dim3(64, 1, 16), TB, 0, stream>>>(
        w_off2, h1, nullptr, b_off2, om2, 48);
    conv_gemm<64,4,4,2,1,128,128,64,64,2><<<dim3(64, 2, 16), TB, 0, stream>>>(
        w2, h1, om2, b2, skip2, 128);
    instnorm_k<true,false,false><<<16 * 128, TB, 0, stream>>>(skip2, skip2, nullptr, 4096);

    // ---- Stage 3: 4x4 s2 p1, 128 -> 256ch @32x32
    conv_gemm<128,4,4,2,1,64,64,32,32,0><<<dim3(16, 1, 16), TB, 0, stream>>>(
        w_off3, skip2, nullptr, b_off3, om3, 48);
    conv_gemm<128,4,4,2,1,64,64,32,32,2><<<dim3(16, 4, 16), TB, 0, stream>>>(
        w3, skip2, om3, b3, skip3, 256);
    // IN+ReLU into skip3, dual-write to initialize h
    instnorm_k<true,true,false><<<16 * 256, TB, 0, stream>>>(skip3, skip3, h_out, 1024);

    // ---- Residual blocks: reflect-pad 3x3, 256 -> 256 @32x32
    for (int r = 0; r < 2; ++r) {
        conv_gemm<256,3,3,1,1,32,32,32,32,1><<<dim3(16, 4, 16), TB, 0, stream>>>(
            rwa[r], h_out, nullptr, rba[r], y1, 256);
        instnorm_k<true,false,false><<<16 * 256, TB, 0, stream>>>(y1, y1, nullptr, 1024);
        conv_gemm<256,3,3,1,1,32,32,32,32,1><<<dim3(16, 4, 16), TB, 0, stream>>>(
            rwb[r], y1, nullptr, rbb[r], y2, 256);
        instnorm_k<false,false,true><<<16 * 256, TB, 0, stream>>>(y2, h_out, nullptr, 1024);
    }
}

// Round 3
// 2916.279 us; speedup vs baseline: 1.5865x; 1.5865x over previous
//
#include <hip/hip_runtime.h>
#include <math.h>

typedef __attribute__((ext_vector_type(8))) short short8;
typedef __attribute__((ext_vector_type(4))) float floatx4;

__device__ __forceinline__ unsigned short f2bf(float f) {
    unsigned u = __builtin_bit_cast(unsigned, f);
    u += 0x7FFFu + ((u >> 16) & 1u);   // RNE
    return (unsigned short)(u >> 16);
}

// Implicit-GEMM conv on bf16 MFMA: Out[z][m][n] = sum_k A[m][k]*B(k,n) + bias[m]
// MODE 0: zero-pad im2col  MODE 1: reflect-pad im2col  MODE 2: deform bilinear*sigmoid(mask)
// Tile: BM=BN=64, BK=64. 256 threads = 4 waves; wave w owns rows [16w,16w+16).
// LDS: As[m][k], Bs[n][k] bf16, 16B k-groups XOR-swizzled by (row&7).
template<int CIN,int KH,int KW,int STR,int PAD,int H,int W,int HO,int WO,int MODE>
__global__ __launch_bounds__(256) void conv_mfma(
    const float* __restrict__ A,      // [M x Ktot] weights (OIHW flat)
    const float* __restrict__ X,      // [Z][CIN][H][W]
    const float* __restrict__ OM,     // [Z][3*Kk][HO][WO] (deform only)
    const float* __restrict__ bias,   // [M]
    float* __restrict__ Out,          // [Z][M][HO*WO]
    int M)
{
    constexpr int Kk   = KH*KW;
    constexpr int Ktot = CIN*Kk;
    constexpr int HWc  = H*W;
    constexpr int HOWO = HO*WO;
    constexpr int KT   = (Ktot + 63) & ~63;
    constexpr bool FASTA = (Ktot % 64 == 0);

    const int z = blockIdx.z;
    const float* __restrict__ Xb  = X + (size_t)z * CIN * HWc;
    const float* __restrict__ OMb = (MODE == 2) ? (OM + (size_t)z * 3 * Kk * HOWO) : nullptr;
    float* __restrict__ Outb = Out + (size_t)z * (size_t)M * HOWO;

    const int n0   = blockIdx.x * 64;
    const int m0   = blockIdx.y * 64;
    const int tid  = threadIdx.x;
    const int lane = tid & 63;
    const int wave = tid >> 6;
    const int quad = lane >> 4;
    const int l16  = lane & 15;

    __shared__ unsigned short As[64][64];
    __shared__ unsigned short Bs[64][64];

    floatx4 acc[4];
#pragma unroll
    for (int t = 0; t < 4; ++t) acc[t] = (floatx4){0.f, 0.f, 0.f, 0.f};

    // staging maps
    const int am  = tid >> 2;   // A: row 0..63
    const int akc = tid & 3;    // A: 16-float chunk
    const int bn  = tid >> 3;   // B: n 0..31 (+32 second half)
    const int bkc = tid & 7;    // B: 8-k chunk

    for (int k0 = 0; k0 < KT; k0 += 64) {
        // ---- stage A tile (fp32 global -> bf16 LDS)
        {
            const int gm = m0 + am;
            unsigned short tmp[16];
            if constexpr (FASTA) {
                if (gm < M) {
                    const float4* p = (const float4*)(A + (size_t)gm * Ktot + k0 + akc * 16);
                    float4 f0 = p[0], f1 = p[1], f2 = p[2], f3 = p[3];
                    tmp[0]=f2bf(f0.x); tmp[1]=f2bf(f0.y); tmp[2]=f2bf(f0.z); tmp[3]=f2bf(f0.w);
                    tmp[4]=f2bf(f1.x); tmp[5]=f2bf(f1.y); tmp[6]=f2bf(f1.z); tmp[7]=f2bf(f1.w);
                    tmp[8]=f2bf(f2.x); tmp[9]=f2bf(f2.y); tmp[10]=f2bf(f2.z); tmp[11]=f2bf(f2.w);
                    tmp[12]=f2bf(f3.x); tmp[13]=f2bf(f3.y); tmp[14]=f2bf(f3.z); tmp[15]=f2bf(f3.w);
                } else {
#pragma unroll
                    for (int j = 0; j < 16; ++j) tmp[j] = 0;
                }
            } else {
#pragma unroll
                for (int j = 0; j < 16; ++j) {
                    int gk = k0 + akc * 16 + j;
                    float v = (gm < M && gk < Ktot) ? A[(size_t)gm * Ktot + gk] : 0.f;
                    tmp[j] = f2bf(v);
                }
            }
            short8 s0, s1;
#pragma unroll
            for (int j = 0; j < 8; ++j) { s0[j] = (short)tmp[j]; s1[j] = (short)tmp[8 + j]; }
            const int g0 = (akc * 2)     ^ (am & 7);
            const int g1 = (akc * 2 + 1) ^ (am & 7);
            *(short8*)&As[am][g0 * 8] = s0;
            *(short8*)&As[am][g1 * 8] = s1;
        }

        // ---- stage B tile (sampled -> bf16 LDS)
#pragma unroll
        for (int half = 0; half < 2; ++half) {
            const int n  = bn + half * 32;
            const int gn = n0 + n;
            const int ho = gn / WO, wo = gn % WO;
            unsigned short tmp[8];
#pragma unroll
            for (int j = 0; j < 8; ++j) {
                int gk = k0 + bkc * 8 + j;
                float v = 0.f;
                if (gk < Ktot) {
                    int ci = gk / Kk;
                    int r  = gk % Kk;
                    int ky = r / KW, kx = r % KW;
                    if constexpr (MODE == 0) {
                        int iy = ho * STR - PAD + ky;
                        int ix = wo * STR - PAD + kx;
                        if (iy >= 0 && iy < H && ix >= 0 && ix < W)
                            v = Xb[(size_t)ci * HWc + iy * W + ix];
                    } else if constexpr (MODE == 1) {
                        int iy = ho - PAD + ky; iy = iy < 0 ? -iy : (iy >= H ? 2 * H - 2 - iy : iy);
                        int ix = wo - PAD + kx; ix = ix < 0 ? -ix : (ix >= W ? 2 * W - 2 - ix : ix);
                        v = Xb[(size_t)ci * HWc + iy * W + ix];
                    } else {
                        // off = concat(o1,o2).reshape(K,2,..): offy=ch 2r, offx=ch 2r+1, mask=2K+r
                        const float* img = Xb + (size_t)ci * HWc;
                        float offy = OMb[(size_t)(2 * r) * HOWO + gn];
                        float offx = OMb[(size_t)(2 * r + 1) * HOWO + gn];
                        float ml   = OMb[(size_t)(2 * Kk + r) * HOWO + gn];
                        float mask = 1.f / (1.f + expf(-ml));
                        float ys = (float)(ho * STR - PAD + ky) + offy;
                        float xs = (float)(wo * STR - PAD + kx) + offx;
                        float y0f = floorf(ys), x0f = floorf(xs);
                        float dy = ys - y0f, dx = xs - x0f;
                        int y0 = (int)y0f, x0 = (int)x0f;
                        float v00 = 0.f, v01 = 0.f, v10 = 0.f, v11 = 0.f;
                        bool y0ok = (y0 >= 0) & (y0 < H), y1ok = (y0 + 1 >= 0) & (y0 + 1 < H);
                        bool x0ok = (x0 >= 0) & (x0 < W), x1ok = (x0 + 1 >= 0) & (x0 + 1 < W);
                        if (y0ok && x0ok) v00 = img[y0 * W + x0];
                        if (y0ok && x1ok) v01 = img[y0 * W + x0 + 1];
                        if (y1ok && x0ok) v10 = img[(y0 + 1) * W + x0];
                        if (y1ok && x1ok) v11 = img[(y0 + 1) * W + x0 + 1];
                        v = (v00 * (1.f - dy) * (1.f - dx) + v01 * (1.f - dy) * dx +
                             v10 * dy * (1.f - dx) + v11 * dy * dx) * mask;
                    }
                }
                tmp[j] = f2bf(v);
            }
            short8 s;
#pragma unroll
            for (int j = 0; j < 8; ++j) s[j] = (short)tmp[j];
            *(short8*)&Bs[n][((bkc ^ (n & 7)) * 8)] = s;
        }
        __syncthreads();

        // ---- MFMA: wave computes 16(m) x 64(n), K=64
        {
            const int mrow = wave * 16 + l16;
#pragma unroll
            for (int kk = 0; kk < 2; ++kk) {
                const int kg = kk * 4 + quad;
                short8 a = *(const short8*)&As[mrow][((kg ^ (mrow & 7)) * 8)];
#pragma unroll
                for (int t = 0; t < 4; ++t) {
                    const int ncol = t * 16 + l16;
                    short8 b = *(const short8*)&Bs[ncol][((kg ^ (ncol & 7)) * 8)];
                    acc[t] = __builtin_amdgcn_mfma_f32_16x16x32_bf16(a, b, acc[t], 0, 0, 0);
                }
            }
        }
        __syncthreads();
    }

    // ---- epilogue: bias + store. D layout: row = quad*4+i, col = lane&15
    float bia[4];
#pragma unroll
    for (int i = 0; i < 4; ++i) {
        int mg = m0 + wave * 16 + quad * 4 + i;
        bia[i] = (mg < M) ? bias[mg] : 0.f;
    }
#pragma unroll
    for (int t = 0; t < 4; ++t) {
        const int ng = n0 + t * 16 + l16;
#pragma unroll
        for (int i = 0; i < 4; ++i) {
            int mg = m0 + wave * 16 + quad * 4 + i;
            if (mg < M)
                Outb[(size_t)mg * HOWO + ng] = acc[t][i] + bia[i];
        }
    }
}

// Instance norm over HW per (b,c) block; optional ReLU, dual-write, add-into-out.
template<bool RELU, bool DUAL, bool ADDIN>
__global__ __launch_bounds__(256) void instnorm_k(
    const float* __restrict__ in, float* __restrict__ out,
    float* __restrict__ out2, int HW)
{
    const int bc = blockIdx.x;
    const float* p = in + (size_t)bc * HW;
    float s = 0.f, ss = 0.f;
    for (int i = threadIdx.x; i < HW; i += 256) { float v = p[i]; s += v; ss += v * v; }
    __shared__ float rs[256], rq[256];
    rs[threadIdx.x] = s; rq[threadIdx.x] = ss;
    __syncthreads();
    for (int o = 128; o > 0; o >>= 1) {
        if (threadIdx.x < o) { rs[threadIdx.x] += rs[threadIdx.x + o]; rq[threadIdx.x] += rq[threadIdx.x + o]; }
        __syncthreads();
    }
    float mean = rs[0] / (float)HW;
    float var  = rq[0] / (float)HW - mean * mean;
    float inv  = rsqrtf(var + 1e-5f);
    float* q  = out + (size_t)bc * HW;
    float* q2 = DUAL ? (out2 + (size_t)bc * HW) : nullptr;
    for (int i = threadIdx.x; i < HW; i += 256) {
        float v = (p[i] - mean) * inv;
        if (RELU) v = fmaxf(v, 0.f);
        if (ADDIN) {
            q[i] = q[i] + v;
        } else {
            q[i] = v;
            if (DUAL) q2[i] = v;
        }
    }
}

extern "C" void kernel_launch(void* const* d_in, const int* in_sizes, int n_in,
                              void* d_out, int out_size, void* d_ws, size_t ws_size,
                              hipStream_t stream)
{
    const float* x      = (const float*)d_in[0];
    const float* w_off1 = (const float*)d_in[1];
    const float* b_off1 = (const float*)d_in[2];
    const float* w1     = (const float*)d_in[3];
    const float* b1     = (const float*)d_in[4];
    const float* w_off2 = (const float*)d_in[5];
    const float* b_off2 = (const float*)d_in[6];
    const float* w2     = (const float*)d_in[7];
    const float* b2     = (const float*)d_in[8];
    const float* w_off3 = (const float*)d_in[9];
    const float* b_off3 = (const float*)d_in[10];
    const float* w3     = (const float*)d_in[11];
    const float* b3     = (const float*)d_in[12];
    const float* rwa[2] = {(const float*)d_in[13], (const float*)d_in[17]};
    const float* rba[2] = {(const float*)d_in[14], (const float*)d_in[18]};
    const float* rwb[2] = {(const float*)d_in[15], (const float*)d_in[19]};
    const float* rbb[2] = {(const float*)d_in[16], (const float*)d_in[20]};

    float* out   = (float*)d_out;
    float* h_out = out;                         // [16,256,32,32]
    float* skip2 = out + 4194304;               // [16,128,64,64]
    float* skip3 = out + 4194304 + 8388608;     // [16,256,32,32]

    // workspace layout (floats). om1 (stage-1, 4-batch chunks) aliases the later pool.
    float* wsf  = (float*)d_ws;
    float* h1   = wsf;                      // 16,777,216  [16,64,128,128]
    float* pool = h1 + 16777216;
    float* om2  = pool;                     // 3,145,728   [16,48,64,64]
    float* om3  = om2 + 3145728;            //   786,432   [16,48,32,32]
    float* y1   = om3 + 786432;             // 4,194,304   [16,256,32,32]
    float* y2   = y1 + 4194304;             // 4,194,304
    float* om1  = pool;                     // 9,633,792 per 4-batch chunk (dead before stage 2)

    // ---- Stage 1: 7x7 s1 p3, Cin=3 -> 64ch @128x128 (4-batch chunks to bound om1)
    for (int c = 0; c < 4; ++c) {
        const float* xc = x + (size_t)c * 4 * 3 * 16384;
        conv_mfma<3,7,7,1,3,128,128,128,128,0><<<dim3(256, 3, 4), 256, 0, stream>>>(
            w_off1, xc, nullptr, b_off1, om1, 147);
        conv_mfma<3,7,7,1,3,128,128,128,128,2><<<dim3(256, 1, 4), 256, 0, stream>>>(
            w1, xc, om1, b1, h1 + (size_t)c * 4 * 64 * 16384, 64);
    }
    instnorm_k<true,false,false><<<16 * 64, 256, 0, stream>>>(h1, h1, nullptr, 16384);

    // ---- Stage 2: 4x4 s2 p1, 64 -> 128ch @64x64
    conv_mfma<64,4,4,2,1,128,128,64,64,0><<<dim3(64, 1, 16), 256, 0, stream>>>(
        w_off2, h1, nullptr, b_off2, om2, 48);
    conv_mfma<64,4,4,2,1,128,128,64,64,2><<<dim3(64, 2, 16), 256, 0, stream>>>(
        w2, h1, om2, b2, skip2, 128);
    instnorm_k<true,false,false><<<16 * 128, 256, 0, stream>>>(skip2, skip2, nullptr, 4096);

    // ---- Stage 3: 4x4 s2 p1, 128 -> 256ch @32x32
    conv_mfma<128,4,4,2,1,64,64,32,32,0><<<dim3(16, 1, 16), 256, 0, stream>>>(
        w_off3, skip2, nullptr, b_off3, om3, 48);
    conv_mfma<128,4,4,2,1,64,64,32,32,2><<<dim3(16, 4, 16), 256, 0, stream>>>(
        w3, skip2, om3, b3, skip3, 256);
    instnorm_k<true,true,false><<<16 * 256, 256, 0, stream>>>(skip3, skip3, h_out, 1024);

    // ---- Residual blocks: reflect-pad 3x3, 256 -> 256 @32x32
    for (int r = 0; r < 2; ++r) {
        conv_mfma<256,3,3,1,1,32,32,32,32,1><<<dim3(16, 4, 16), 256, 0, stream>>>(
            rwa[r], h_out, nullptr, rba[r], y1, 256);
        instnorm_k<true,false,false><<<16 * 256, 256, 0, stream>>>(y1, y1, nullptr, 1024);
        conv_mfma<256,3,3,1,1,32,32,32,32,1><<<dim3(16, 4, 16), 256, 0, stream>>>(
            rwb[r], y1, nullptr, rbb[r], y2, 256);
        instnorm_k<false,false,true><<<16 * 256, 256, 0, stream>>>(y2, h_out, nullptr, 1024);
    }
}

// Round 4
// 2555.390 us; speedup vs baseline: 1.8106x; 1.1412x over previous
//
#include <hip/hip_runtime.h>
#include <math.h>

typedef __attribute__((ext_vector_type(8))) short short8;
typedef __attribute__((ext_vector_type(4))) float floatx4;

__device__ __forceinline__ unsigned short f2bf(float f) {
    unsigned u = __builtin_bit_cast(unsigned, f);
    u += 0x7FFFu + ((u >> 16) & 1u);   // RNE
    return (unsigned short)(u >> 16);
}

// Implicit-GEMM conv on bf16 MFMA: Out[z][m][n] = sum_k A[m][k]*B(k,n) + bias[m]
// MODE 0: zero-pad im2col  MODE 1: reflect-pad im2col  MODE 2: deform bilinear*sigmoid(mask)
// Tile: BM=BN=64, BK=64. 256 threads = 4 waves; wave w owns rows [16w,16w+16).
// LDS: As[m][k], Bs[n][k] bf16, 16B k-groups XOR-swizzled by (row&7).
// Sampling metadata (indices/weights per (n,r)) hoisted to LDS before the K-loop:
// it depends only on (n,r), and is otherwise recomputed Cin times (64-256x).
template<int CIN,int KH,int KW,int STR,int PAD,int H,int W,int HO,int WO,int MODE>
__global__ __launch_bounds__(256) void conv_mfma(
    const float* __restrict__ A,      // [M x Ktot] weights (OIHW flat)
    const float* __restrict__ X,      // [Z][CIN][H][W]
    const float* __restrict__ OM,     // [Z][3*Kk][HO][WO] (deform only)
    const float* __restrict__ bias,   // [M]
    float* __restrict__ Out,          // [Z][M][HO*WO]
    int M)
{
    constexpr int Kk   = KH*KW;
    constexpr int Ktot = CIN*Kk;
    constexpr int HWc  = H*W;
    constexpr int HOWO = HO*WO;
    constexpr int KT   = (Ktot + 63) & ~63;
    constexpr bool FASTA  = (Ktot % 64 == 0);
    constexpr bool META2  = (MODE == 2) && (Kk <= 16);   // deform idx+weight meta
    constexpr bool META01 = (MODE != 2);                 // gather-idx meta
    constexpr int KPAD = (Kk % 2 == 0) ? Kk + 1 : Kk;    // bank-friendly stride

    const int z = blockIdx.z;
    const float* __restrict__ Xb  = X + (size_t)z * CIN * HWc;
    const float* __restrict__ OMb = (MODE == 2) ? (OM + (size_t)z * 3 * Kk * HOWO) : nullptr;
    float* __restrict__ Outb = Out + (size_t)z * (size_t)M * HOWO;

    const int n0   = blockIdx.x * 64;
    const int m0   = blockIdx.y * 64;
    const int tid  = threadIdx.x;
    const int lane = tid & 63;
    const int wave = tid >> 6;
    const int quad = lane >> 4;
    const int l16  = lane & 15;

    __shared__ unsigned short As[64][64];
    __shared__ unsigned short Bs[64][64];
    __shared__ int4   MI[META2 ? 64 * KPAD : 1];
    __shared__ float4 MW[META2 ? 64 * KPAD : 1];
    __shared__ int    MI0[META01 ? 64 * KPAD : 1];

    // ---- precompute sampling metadata for the block's 64 n's x Kk taps
    if constexpr (META2) {
        for (int e = tid; e < 64 * Kk; e += 256) {
            int n = e / Kk, r = e - n * Kk;
            int gn = n0 + n, ho = gn / WO, wo = gn % WO;
            int ky = r / KW, kx = r % KW;
            float offy = OMb[(size_t)(2 * r) * HOWO + gn];
            float offx = OMb[(size_t)(2 * r + 1) * HOWO + gn];
            float ml   = OMb[(size_t)(2 * Kk + r) * HOWO + gn];
            float mask = 1.f / (1.f + expf(-ml));
            float ys = (float)(ho * STR - PAD + ky) + offy;
            float xs = (float)(wo * STR - PAD + kx) + offx;
            float y0f = floorf(ys), x0f = floorf(xs);
            float dy = ys - y0f, dx = xs - x0f;
            int y0 = (int)y0f, x0 = (int)x0f;
            int4 ii; float4 ww;
            int yc0 = min(max(y0, 0), H - 1), yc1 = min(max(y0 + 1, 0), H - 1);
            int xc0 = min(max(x0, 0), W - 1), xc1 = min(max(x0 + 1, 0), W - 1);
            bool y0ok = (y0 >= 0) & (y0 < H), y1ok = (y0 + 1 >= 0) & (y0 + 1 < H);
            bool x0ok = (x0 >= 0) & (x0 < W), x1ok = (x0 + 1 >= 0) & (x0 + 1 < W);
            ii.x = yc0 * W + xc0; ii.y = yc0 * W + xc1;
            ii.z = yc1 * W + xc0; ii.w = yc1 * W + xc1;
            ww.x = (y0ok && x0ok) ? (1.f - dy) * (1.f - dx) * mask : 0.f;
            ww.y = (y0ok && x1ok) ? (1.f - dy) * dx * mask : 0.f;
            ww.z = (y1ok && x0ok) ? dy * (1.f - dx) * mask : 0.f;
            ww.w = (y1ok && x1ok) ? dy * dx * mask : 0.f;
            MI[n * KPAD + r] = ii; MW[n * KPAD + r] = ww;
        }
        __syncthreads();
    }
    if constexpr (META01) {
        for (int e = tid; e < 64 * Kk; e += 256) {
            int n = e / Kk, r = e - n * Kk;
            int gn = n0 + n, ho = gn / WO, wo = gn % WO;
            int ky = r / KW, kx = r % KW;
            int idx;
            if constexpr (MODE == 0) {
                int iy = ho * STR - PAD + ky;
                int ix = wo * STR - PAD + kx;
                idx = (iy >= 0 && iy < H && ix >= 0 && ix < W) ? iy * W + ix : -1;
            } else {
                int iy = ho - PAD + ky; iy = iy < 0 ? -iy : (iy >= H ? 2 * H - 2 - iy : iy);
                int ix = wo - PAD + kx; ix = ix < 0 ? -ix : (ix >= W ? 2 * W - 2 - ix : ix);
                idx = iy * W + ix;
            }
            MI0[n * KPAD + r] = idx;
        }
        __syncthreads();
    }

    floatx4 acc[4];
#pragma unroll
    for (int t = 0; t < 4; ++t) acc[t] = (floatx4){0.f, 0.f, 0.f, 0.f};

    // staging maps
    const int am  = tid >> 2;   // A: row 0..63
    const int akc = tid & 3;    // A: 16-float chunk
    const int bn  = tid >> 3;   // B: n 0..31 (+32 second half)
    const int bkc = tid & 7;    // B: 8-k chunk

    for (int k0 = 0; k0 < KT; k0 += 64) {
        // ---- stage A tile (fp32 global -> bf16 LDS)
        {
            const int gm = m0 + am;
            unsigned short tmp[16];
            if constexpr (FASTA) {
                if (gm < M) {
                    const float4* p = (const float4*)(A + (size_t)gm * Ktot + k0 + akc * 16);
                    float4 f0 = p[0], f1 = p[1], f2 = p[2], f3 = p[3];
                    tmp[0]=f2bf(f0.x); tmp[1]=f2bf(f0.y); tmp[2]=f2bf(f0.z); tmp[3]=f2bf(f0.w);
                    tmp[4]=f2bf(f1.x); tmp[5]=f2bf(f1.y); tmp[6]=f2bf(f1.z); tmp[7]=f2bf(f1.w);
                    tmp[8]=f2bf(f2.x); tmp[9]=f2bf(f2.y); tmp[10]=f2bf(f2.z); tmp[11]=f2bf(f2.w);
                    tmp[12]=f2bf(f3.x); tmp[13]=f2bf(f3.y); tmp[14]=f2bf(f3.z); tmp[15]=f2bf(f3.w);
                } else {
#pragma unroll
                    for (int j = 0; j < 16; ++j) tmp[j] = 0;
                }
            } else {
#pragma unroll
                for (int j = 0; j < 16; ++j) {
                    int gk = k0 + akc * 16 + j;
                    float v = (gm < M && gk < Ktot) ? A[(size_t)gm * Ktot + gk] : 0.f;
                    tmp[j] = f2bf(v);
                }
            }
            short8 s0, s1;
#pragma unroll
            for (int j = 0; j < 8; ++j) { s0[j] = (short)tmp[j]; s1[j] = (short)tmp[8 + j]; }
            const int g0 = (akc * 2)     ^ (am & 7);
            const int g1 = (akc * 2 + 1) ^ (am & 7);
            *(short8*)&As[am][g0 * 8] = s0;
            *(short8*)&As[am][g1 * 8] = s1;
        }

        // ---- stage B tile (sampled -> bf16 LDS)
#pragma unroll
        for (int half = 0; half < 2; ++half) {
            const int n  = bn + half * 32;
            const int gn = n0 + n;
            unsigned short tmp[8];
            if constexpr (META2) {
                // Kk<=16 and 64%Kk==0 for Kk=16: ci fixed across the 8-j chunk when Kk==16
#pragma unroll
                for (int j = 0; j < 8; ++j) {
                    int gk = k0 + bkc * 8 + j;
                    float v = 0.f;
                    if (gk < Ktot) {
                        int ci, r;
                        if constexpr (Kk == 16) { ci = gk >> 4; r = gk & 15; }
                        else { ci = gk / Kk; r = gk - ci * Kk; }
                        const float* img = Xb + (size_t)ci * HWc;
                        int4 ii = MI[n * KPAD + r];
                        float4 ww = MW[n * KPAD + r];
                        v = ww.x * img[ii.x] + ww.y * img[ii.y] +
                            ww.z * img[ii.z] + ww.w * img[ii.w];
                    }
                    tmp[j] = f2bf(v);
                }
            } else if constexpr (META01) {
#pragma unroll
                for (int j = 0; j < 8; ++j) {
                    int gk = k0 + bkc * 8 + j;
                    float v = 0.f;
                    if (gk < Ktot) {
                        int ci, r;
                        if constexpr (Kk == 16) { ci = gk >> 4; r = gk & 15; }
                        else { ci = gk / Kk; r = gk - ci * Kk; }
                        int idx = MI0[n * KPAD + r];
                        if (MODE == 1 || idx >= 0)
                            v = Xb[(size_t)ci * HWc + idx];
                    }
                    tmp[j] = f2bf(v);
                }
            } else {
                // direct deform path (stage 1: Kk=49, meta too large for LDS)
                const int ho = gn / WO, wo = gn % WO;
#pragma unroll
                for (int j = 0; j < 8; ++j) {
                    int gk = k0 + bkc * 8 + j;
                    float v = 0.f;
                    if (gk < Ktot) {
                        int ci = gk / Kk;
                        int r  = gk - ci * Kk;
                        int ky = r / KW, kx = r % KW;
                        const float* img = Xb + (size_t)ci * HWc;
                        float offy = OMb[(size_t)(2 * r) * HOWO + gn];
                        float offx = OMb[(size_t)(2 * r + 1) * HOWO + gn];
                        float ml   = OMb[(size_t)(2 * Kk + r) * HOWO + gn];
                        float mask = 1.f / (1.f + expf(-ml));
                        float ys = (float)(ho * STR - PAD + ky) + offy;
                        float xs = (float)(wo * STR - PAD + kx) + offx;
                        float y0f = floorf(ys), x0f = floorf(xs);
                        float dy = ys - y0f, dx = xs - x0f;
                        int y0 = (int)y0f, x0 = (int)x0f;
                        float v00 = 0.f, v01 = 0.f, v10 = 0.f, v11 = 0.f;
                        bool y0ok = (y0 >= 0) & (y0 < H), y1ok = (y0 + 1 >= 0) & (y0 + 1 < H);
                        bool x0ok = (x0 >= 0) & (x0 < W), x1ok = (x0 + 1 >= 0) & (x0 + 1 < W);
                        if (y0ok && x0ok) v00 = img[y0 * W + x0];
                        if (y0ok && x1ok) v01 = img[y0 * W + x0 + 1];
                        if (y1ok && x0ok) v10 = img[(y0 + 1) * W + x0];
                        if (y1ok && x1ok) v11 = img[(y0 + 1) * W + x0 + 1];
                        v = (v00 * (1.f - dy) * (1.f - dx) + v01 * (1.f - dy) * dx +
                             v10 * dy * (1.f - dx) + v11 * dy * dx) * mask;
                    }
                    tmp[j] = f2bf(v);
                }
            }
            short8 s;
#pragma unroll
            for (int j = 0; j < 8; ++j) s[j] = (short)tmp[j];
            *(short8*)&Bs[n][((bkc ^ (n & 7)) * 8)] = s;
        }
        __syncthreads();

        // ---- MFMA: wave computes 16(m) x 64(n), K=64
        {
            const int mrow = wave * 16 + l16;
#pragma unroll
            for (int kk = 0; kk < 2; ++kk) {
                const int kg = kk * 4 + quad;
                short8 a = *(const short8*)&As[mrow][((kg ^ (mrow & 7)) * 8)];
#pragma unroll
                for (int t = 0; t < 4; ++t) {
                    const int ncol = t * 16 + l16;
                    short8 b = *(const short8*)&Bs[ncol][((kg ^ (ncol & 7)) * 8)];
                    acc[t] = __builtin_amdgcn_mfma_f32_16x16x32_bf16(a, b, acc[t], 0, 0, 0);
                }
            }
        }
        __syncthreads();
    }

    // ---- epilogue: bias + store. D layout: row = quad*4+i, col = lane&15
    float bia[4];
#pragma unroll
    for (int i = 0; i < 4; ++i) {
        int mg = m0 + wave * 16 + quad * 4 + i;
        bia[i] = (mg < M) ? bias[mg] : 0.f;
    }
#pragma unroll
    for (int t = 0; t < 4; ++t) {
        const int ng = n0 + t * 16 + l16;
#pragma unroll
        for (int i = 0; i < 4; ++i) {
            int mg = m0 + wave * 16 + quad * 4 + i;
            if (mg < M)
                Outb[(size_t)mg * HOWO + ng] = acc[t][i] + bia[i];
        }
    }
}

// Instance norm over HW per (b,c) block; optional ReLU, dual-write, add-into-out.
template<bool RELU, bool DUAL, bool ADDIN>
__global__ __launch_bounds__(256) void instnorm_k(
    const float* __restrict__ in, float* __restrict__ out,
    float* __restrict__ out2, int HW)
{
    const int bc = blockIdx.x;
    const float* p = in + (size_t)bc * HW;
    float s = 0.f, ss = 0.f;
    for (int i = threadIdx.x; i < HW; i += 256) { float v = p[i]; s += v; ss += v * v; }
    __shared__ float rs[256], rq[256];
    rs[threadIdx.x] = s; rq[threadIdx.x] = ss;
    __syncthreads();
    for (int o = 128; o > 0; o >>= 1) {
        if (threadIdx.x < o) { rs[threadIdx.x] += rs[threadIdx.x + o]; rq[threadIdx.x] += rq[threadIdx.x + o]; }
        __syncthreads();
    }
    float mean = rs[0] / (float)HW;
    float var  = rq[0] / (float)HW - mean * mean;
    float inv  = rsqrtf(var + 1e-5f);
    float* q  = out + (size_t)bc * HW;
    float* q2 = DUAL ? (out2 + (size_t)bc * HW) : nullptr;
    for (int i = threadIdx.x; i < HW; i += 256) {
        float v = (p[i] - mean) * inv;
        if (RELU) v = fmaxf(v, 0.f);
        if (ADDIN) {
            q[i] = q[i] + v;
        } else {
            q[i] = v;
            if (DUAL) q2[i] = v;
        }
    }
}

extern "C" void kernel_launch(void* const* d_in, const int* in_sizes, int n_in,
                              void* d_out, int out_size, void* d_ws, size_t ws_size,
                              hipStream_t stream)
{
    const float* x      = (const float*)d_in[0];
    const float* w_off1 = (const float*)d_in[1];
    const float* b_off1 = (const float*)d_in[2];
    const float* w1     = (const float*)d_in[3];
    const float* b1     = (const float*)d_in[4];
    const float* w_off2 = (const float*)d_in[5];
    const float* b_off2 = (const float*)d_in[6];
    const float* w2     = (const float*)d_in[7];
    const float* b2     = (const float*)d_in[8];
    const float* w_off3 = (const float*)d_in[9];
    const float* b_off3 = (const float*)d_in[10];
    const float* w3     = (const float*)d_in[11];
    const float* b3     = (const float*)d_in[12];
    const float* rwa[2] = {(const float*)d_in[13], (const float*)d_in[17]};
    const float* rba[2] = {(const float*)d_in[14], (const float*)d_in[18]};
    const float* rwb[2] = {(const float*)d_in[15], (const float*)d_in[19]};
    const float* rbb[2] = {(const float*)d_in[16], (const float*)d_in[20]};

    float* out   = (float*)d_out;
    float* h_out = out;                         // [16,256,32,32]
    float* skip2 = out + 4194304;               // [16,128,64,64]
    float* skip3 = out + 4194304 + 8388608;     // [16,256,32,32]

    // workspace layout (floats). om1 (stage-1, 4-batch chunks) aliases the later pool.
    float* wsf  = (float*)d_ws;
    float* h1   = wsf;                      // 16,777,216  [16,64,128,128]
    float* pool = h1 + 16777216;
    float* om2  = pool;                     // 3,145,728   [16,48,64,64]
    float* om3  = om2 + 3145728;            //   786,432   [16,48,32,32]
    float* y1   = om3 + 786432;             // 4,194,304   [16,256,32,32]
    float* y2   = y1 + 4194304;             // 4,194,304
    float* om1  = pool;                     // 9,633,792 per 4-batch chunk (dead before stage 2)

    // ---- Stage 1: 7x7 s1 p3, Cin=3 -> 64ch @128x128 (4-batch chunks to bound om1)
    for (int c = 0; c < 4; ++c) {
        const float* xc = x + (size_t)c * 4 * 3 * 16384;
        conv_mfma<3,7,7,1,3,128,128,128,128,0><<<dim3(256, 3, 4), 256, 0, stream>>>(
            w_off1, xc, nullptr, b_off1, om1, 147);
        conv_mfma<3,7,7,1,3,128,128,128,128,2><<<dim3(256, 1, 4), 256, 0, stream>>>(
            w1, xc, om1, b1, h1 + (size_t)c * 4 * 64 * 16384, 64);
    }
    instnorm_k<true,false,false><<<16 * 64, 256, 0, stream>>>(h1, h1, nullptr, 16384);

    // ---- Stage 2: 4x4 s2 p1, 64 -> 128ch @64x64
    conv_mfma<64,4,4,2,1,128,128,64,64,0><<<dim3(64, 1, 16), 256, 0, stream>>>(
        w_off2, h1, nullptr, b_off2, om2, 48);
    conv_mfma<64,4,4,2,1,128,128,64,64,2><<<dim3(64, 2, 16), 256, 0, stream>>>(
        w2, h1, om2, b2, skip2, 128);
    instnorm_k<true,false,false><<<16 * 128, 256, 0, stream>>>(skip2, skip2, nullptr, 4096);

    // ---- Stage 3: 4x4 s2 p1, 128 -> 256ch @32x32
    conv_mfma<128,4,4,2,1,64,64,32,32,0><<<dim3(16, 1, 16), 256, 0, stream>>>(
        w_off3, skip2, nullptr, b_off3, om3, 48);
    conv_mfma<128,4,4,2,1,64,64,32,32,2><<<dim3(16, 4, 16), 256, 0, stream>>>(
        w3, skip2, om3, b3, skip3, 256);
    instnorm_k<true,true,false><<<16 * 256, 256, 0, stream>>>(skip3, skip3, h_out, 1024);

    // ---- Residual blocks: reflect-pad 3x3, 256 -> 256 @32x32
    for (int r = 0; r < 2; ++r) {
        conv_mfma<256,3,3,1,1,32,32,32,32,1><<<dim3(16, 4, 16), 256, 0, stream>>>(
            rwa[r], h_out, nullptr, rba[r], y1, 256);
        instnorm_k<true,false,false><<<16 * 256, 256, 0, stream>>>(y1, y1, nullptr, 1024);
        conv_mfma<256,3,3,1,1,32,32,32,32,1><<<dim3(16, 4, 16), 256, 0, stream>>>(
            rwb[r], y1, nullptr, rbb[r], y2, 256);
        instnorm_k<false,false,true><<<16 * 256, 256, 0, stream>>>(y2, h_out, nullptr, 1024);
    }
}

// Round 6
// 1789.275 us; speedup vs baseline: 2.5858x; 1.4282x over previous
//
#include <hip/hip_runtime.h>
#include <math.h>

typedef __attribute__((ext_vector_type(8))) short short8;
typedef __attribute__((ext_vector_type(4))) float floatx4;
typedef __attribute__((ext_vector_type(4))) _Float16 half4;

__device__ __forceinline__ unsigned short f2bf(float f) {
    unsigned u = __builtin_bit_cast(unsigned, f);
    u += 0x7FFFu + ((u >> 16) & 1u);   // RNE
    return (unsigned short)(u >> 16);
}

// Implicit-GEMM conv on bf16 MFMA: Out[z][m][n] = sum_k A[m][k]*B(k,n) + bias[m]
// MODE 0: zero-pad im2col  MODE 1: reflect-pad im2col  MODE 2: deform bilinear*sigmoid(mask)
// Tile: BM=BN=64, BK=64. 256 threads = 4 waves; wave w owns rows [16w,16w+16).
// B-stage is n-major: lane = n, so gathers for a fixed (ci,r) are consecutive
// across lanes (line-shared). Deform meta is a packed base index (independently
// clamped corners + step bits) + mask-premultiplied half4 weights:
//   packed = (yc0*W+xc0) | (xc1-xc0)<<24 | (yc1-yc0)<<25
// Corner addrs base, base+dx, base+dy*W, base+dy*W+dx are the EXACT clamped
// corners for every in/out-of-bounds combination (OOB corners carry weight 0).
template<int CIN,int KH,int KW,int STR,int PAD,int H,int W,int HO,int WO,int MODE>
__global__ __launch_bounds__(256) void conv_mfma(
    const float* __restrict__ A,      // [M x Ktot] weights (OIHW flat)
    const float* __restrict__ X,      // [Z][CIN][H][W]
    const float* __restrict__ OM,     // [Z][3*Kk][HO][WO] (deform only)
    const float* __restrict__ bias,   // [M]
    float* __restrict__ Out,          // [Z][M][HO*WO]
    int M)
{
    constexpr int Kk   = KH*KW;
    constexpr int Ktot = CIN*Kk;
    constexpr int HWc  = H*W;
    constexpr int HOWO = HO*WO;
    constexpr int KT   = (Ktot + 63) & ~63;
    constexpr bool FASTA  = (Ktot % 64 == 0);
    constexpr bool KGUARD = (Ktot % 64 != 0);
    constexpr bool META2  = (MODE == 2) && (Kk == 16);   // deform packed meta
    constexpr bool META01 = (MODE != 2);                 // gather-idx meta
    constexpr int KPAD = (Kk % 2 == 0) ? Kk + 1 : Kk;    // bank-friendly stride

    const int z = blockIdx.z;
    const float* __restrict__ Xb  = X + (size_t)z * CIN * HWc;
    const float* __restrict__ OMb = (MODE == 2) ? (OM + (size_t)z * 3 * Kk * HOWO) : nullptr;
    float* __restrict__ Outb = Out + (size_t)z * (size_t)M * HOWO;

    const int n0   = blockIdx.x * 64;
    const int m0   = blockIdx.y * 64;
    const int tid  = threadIdx.x;
    const int lane = tid & 63;
    const int wave = tid >> 6;
    const int quad = lane >> 4;
    const int l16  = lane & 15;

    __shared__ unsigned short As[64][64];
    __shared__ unsigned short Bs[64][64];
    __shared__ int   MIb[META2 ? 64 * KPAD : 1];
    __shared__ half4 MWh[META2 ? 64 * KPAD : 1];
    __shared__ int   MI0[META01 ? 64 * KPAD : 1];

    // ---- precompute sampling metadata for the block's 64 n's x Kk taps
    if constexpr (META2) {
        for (int e = tid; e < 64 * Kk; e += 256) {
            int n = e / Kk, r = e - n * Kk;
            int gn = n0 + n, ho = gn / WO, wo = gn % WO;
            int ky = r / KW, kx = r % KW;
            float offy = OMb[(size_t)(2 * r) * HOWO + gn];
            float offx = OMb[(size_t)(2 * r + 1) * HOWO + gn];
            float ml   = OMb[(size_t)(2 * Kk + r) * HOWO + gn];
            float mask = 1.f / (1.f + expf(-ml));
            float ys = (float)(ho * STR - PAD + ky) + offy;
            float xs = (float)(wo * STR - PAD + kx) + offx;
            float y0f = floorf(ys), x0f = floorf(xs);
            float dy = ys - y0f, dx = xs - x0f;
            int y0 = (int)y0f, x0 = (int)x0f;
            int yc0 = min(max(y0, 0), H - 1);
            int yc1 = min(max(y0 + 1, 0), H - 1);
            int xc0 = min(max(x0, 0), W - 1);
            int xc1 = min(max(x0 + 1, 0), W - 1);
            bool y0ok = (y0 >= 0) & (y0 < H), y1ok = (y0 + 1 >= 0) & (y0 + 1 < H);
            bool x0ok = (x0 >= 0) & (x0 < W), x1ok = (x0 + 1 >= 0) & (x0 + 1 < W);
            half4 w;
            w[0] = (_Float16)((y0ok && x0ok) ? (1.f - dy) * (1.f - dx) * mask : 0.f);
            w[1] = (_Float16)((y0ok && x1ok) ? (1.f - dy) * dx * mask : 0.f);
            w[2] = (_Float16)((y1ok && x0ok) ? dy * (1.f - dx) * mask : 0.f);
            w[3] = (_Float16)((y1ok && x1ok) ? dy * dx * mask : 0.f);
            MIb[n * KPAD + r] = (yc0 * W + xc0) | ((xc1 - xc0) << 24) | ((yc1 - yc0) << 25);
            MWh[n * KPAD + r] = w;
        }
        __syncthreads();
    }
    if constexpr (META01) {
        for (int e = tid; e < 64 * Kk; e += 256) {
            int n = e / Kk, r = e - n * Kk;
            int gn = n0 + n, ho = gn / WO, wo = gn % WO;
            int ky = r / KW, kx = r % KW;
            int idx;
            if constexpr (MODE == 0) {
                int iy = ho * STR - PAD + ky;
                int ix = wo * STR - PAD + kx;
                idx = (iy >= 0 && iy < H && ix >= 0 && ix < W) ? iy * W + ix : -1;
            } else {
                int iy = ho - PAD + ky; iy = iy < 0 ? -iy : (iy >= H ? 2 * H - 2 - iy : iy);
                int ix = wo - PAD + kx; ix = ix < 0 ? -ix : (ix >= W ? 2 * W - 2 - ix : ix);
                idx = iy * W + ix;
            }
            MI0[n * KPAD + r] = idx;
        }
        __syncthreads();
    }

    floatx4 acc[4];
#pragma unroll
    for (int t = 0; t < 4; ++t) acc[t] = (floatx4){0.f, 0.f, 0.f, 0.f};

    // staging maps
    const int am  = tid >> 2;   // A: row 0..63
    const int akc = tid & 3;    // A: 16-float chunk
    const int bn2 = tid & 63;   // B: n (lane) -> coalesced gathers
    const int bkc = tid >> 6;   // B: 16-k chunk (0..3)
    const int gn2 = n0 + bn2;
    const int ho2 = gn2 / WO, wo2 = gn2 % WO;

    for (int k0 = 0; k0 < KT; k0 += 64) {
        // ---- stage A tile (fp32 global -> bf16 LDS)
        {
            const int gm = m0 + am;
            unsigned short tmp[16];
            if constexpr (FASTA) {
                if (gm < M) {
                    const float4* p = (const float4*)(A + (size_t)gm * Ktot + k0 + akc * 16);
                    float4 f0 = p[0], f1 = p[1], f2 = p[2], f3 = p[3];
                    tmp[0]=f2bf(f0.x); tmp[1]=f2bf(f0.y); tmp[2]=f2bf(f0.z); tmp[3]=f2bf(f0.w);
                    tmp[4]=f2bf(f1.x); tmp[5]=f2bf(f1.y); tmp[6]=f2bf(f1.z); tmp[7]=f2bf(f1.w);
                    tmp[8]=f2bf(f2.x); tmp[9]=f2bf(f2.y); tmp[10]=f2bf(f2.z); tmp[11]=f2bf(f2.w);
                    tmp[12]=f2bf(f3.x); tmp[13]=f2bf(f3.y); tmp[14]=f2bf(f3.z); tmp[15]=f2bf(f3.w);
                } else {
#pragma unroll
                    for (int j = 0; j < 16; ++j) tmp[j] = 0;
                }
            } else {
#pragma unroll
                for (int j = 0; j < 16; ++j) {
                    int gk = k0 + akc * 16 + j;
                    float v = (gm < M && gk < Ktot) ? A[(size_t)gm * Ktot + gk] : 0.f;
                    tmp[j] = f2bf(v);
                }
            }
            short8 s0, s1;
#pragma unroll
            for (int j = 0; j < 8; ++j) { s0[j] = (short)tmp[j]; s1[j] = (short)tmp[8 + j]; }
            const int g0 = (akc * 2)     ^ (am & 7);
            const int g1 = (akc * 2 + 1) ^ (am & 7);
            *(short8*)&As[am][g0 * 8] = s0;
            *(short8*)&As[am][g1 * 8] = s1;
        }

        // ---- stage B tile (sampled -> bf16 LDS), n-major
        {
            unsigned short tmp[16];
            if constexpr (META2) {
                // Kk==16: ci fixed for this thread's 16-k chunk
                const int ci = (k0 >> 4) + bkc;
                const float* img = Xb + (size_t)ci * HWc;
#pragma unroll
                for (int j = 0; j < 16; ++j) {
                    int packed = MIb[bn2 * KPAD + j];
                    half4 w    = MWh[bn2 * KPAD + j];
                    int base = packed & 0xFFFFFF;
                    int dxs  = (packed >> 24) & 1;
                    int dys  = ((packed >> 25) & 1) ? W : 0;
                    float v = (float)w[0] * img[base]
                            + (float)w[1] * img[base + dxs]
                            + (float)w[2] * img[base + dys]
                            + (float)w[3] * img[base + dys + dxs];
                    tmp[j] = f2bf(v);
                }
            } else if constexpr (META01) {
#pragma unroll
                for (int j = 0; j < 16; ++j) {
                    int gk = k0 + bkc * 16 + j;
                    float v = 0.f;
                    if (!KGUARD || gk < Ktot) {
                        int ci, r;
                        if constexpr (Kk == 16) { ci = gk >> 4; r = gk & 15; }
                        else { ci = gk / Kk; r = gk - ci * Kk; }
                        int idx = MI0[bn2 * KPAD + r];
                        if (MODE == 1 || idx >= 0)
                            v = Xb[(size_t)ci * HWc + idx];
                    }
                    tmp[j] = f2bf(v);
                }
            } else {
                // direct deform path (stage 1: Kk=49, meta too large for LDS)
#pragma unroll 4
                for (int j = 0; j < 16; ++j) {
                    int gk = k0 + bkc * 16 + j;
                    float v = 0.f;
                    if (!KGUARD || gk < Ktot) {
                        int ci = gk / Kk;
                        int r  = gk - ci * Kk;
                        int ky = r / KW, kx = r % KW;
                        const float* img = Xb + (size_t)ci * HWc;
                        float offy = OMb[(size_t)(2 * r) * HOWO + gn2];
                        float offx = OMb[(size_t)(2 * r + 1) * HOWO + gn2];
                        float ml   = OMb[(size_t)(2 * Kk + r) * HOWO + gn2];
                        float mask = 1.f / (1.f + expf(-ml));
                        float ys = (float)(ho2 * STR - PAD + ky) + offy;
                        float xs = (float)(wo2 * STR - PAD + kx) + offx;
                        float y0f = floorf(ys), x0f = floorf(xs);
                        float dy = ys - y0f, dx = xs - x0f;
                        int y0 = (int)y0f, x0 = (int)x0f;
                        float v00 = 0.f, v01 = 0.f, v10 = 0.f, v11 = 0.f;
                        bool y0ok = (y0 >= 0) & (y0 < H), y1ok = (y0 + 1 >= 0) & (y0 + 1 < H);
                        bool x0ok = (x0 >= 0) & (x0 < W), x1ok = (x0 + 1 >= 0) & (x0 + 1 < W);
                        if (y0ok && x0ok) v00 = img[y0 * W + x0];
                        if (y0ok && x1ok) v01 = img[y0 * W + x0 + 1];
                        if (y1ok && x0ok) v10 = img[(y0 + 1) * W + x0];
                        if (y1ok && x1ok) v11 = img[(y0 + 1) * W + x0 + 1];
                        v = (v00 * (1.f - dy) * (1.f - dx) + v01 * (1.f - dy) * dx +
                             v10 * dy * (1.f - dx) + v11 * dy * dx) * mask;
                    }
                    tmp[j] = f2bf(v);
                }
            }
            short8 s0, s1;
#pragma unroll
            for (int j = 0; j < 8; ++j) { s0[j] = (short)tmp[j]; s1[j] = (short)tmp[8 + j]; }
            const int g0 = (bkc * 2)     ^ (bn2 & 7);
            const int g1 = (bkc * 2 + 1) ^ (bn2 & 7);
            *(short8*)&Bs[bn2][g0 * 8] = s0;
            *(short8*)&Bs[bn2][g1 * 8] = s1;
        }
        __syncthreads();

        // ---- MFMA: wave computes 16(m) x 64(n), K=64
        {
            const int mrow = wave * 16 + l16;
#pragma unroll
            for (int kk = 0; kk < 2; ++kk) {
                const int kg = kk * 4 + quad;
                short8 a = *(const short8*)&As[mrow][((kg ^ (mrow & 7)) * 8)];
#pragma unroll
                for (int t = 0; t < 4; ++t) {
                    const int ncol = t * 16 + l16;
                    short8 b = *(const short8*)&Bs[ncol][((kg ^ (ncol & 7)) * 8)];
                    acc[t] = __builtin_amdgcn_mfma_f32_16x16x32_bf16(a, b, acc[t], 0, 0, 0);
                }
            }
        }
        __syncthreads();
    }

    // ---- epilogue: bias + store. D layout: row = quad*4+i, col = lane&15
    float bia[4];
#pragma unroll
    for (int i = 0; i < 4; ++i) {
        int mg = m0 + wave * 16 + quad * 4 + i;
        bia[i] = (mg < M) ? bias[mg] : 0.f;
    }
#pragma unroll
    for (int t = 0; t < 4; ++t) {
        const int ng = n0 + t * 16 + l16;
#pragma unroll
        for (int i = 0; i < 4; ++i) {
            int mg = m0 + wave * 16 + quad * 4 + i;
            if (mg < M)
                Outb[(size_t)mg * HOWO + ng] = acc[t][i] + bia[i];
        }
    }
}

// Instance norm over HW per (b,c) block; optional ReLU, dual-write, add-into-out.
template<bool RELU, bool DUAL, bool ADDIN>
__global__ __launch_bounds__(256) void instnorm_k(
    const float* __restrict__ in, float* __restrict__ out,
    float* __restrict__ out2, int HW)
{
    const int bc = blockIdx.x;
    const float* p = in + (size_t)bc * HW;
    float s = 0.f, ss = 0.f;
    for (int i = threadIdx.x; i < HW; i += 256) { float v = p[i]; s += v; ss += v * v; }
    __shared__ float rs[256], rq[256];
    rs[threadIdx.x] = s; rq[threadIdx.x] = ss;
    __syncthreads();
    for (int o = 128; o > 0; o >>= 1) {
        if (threadIdx.x < o) { rs[threadIdx.x] += rs[threadIdx.x + o]; rq[threadIdx.x] += rq[threadIdx.x + o]; }
        __syncthreads();
    }
    float mean = rs[0] / (float)HW;
    float var  = rq[0] / (float)HW - mean * mean;
    float inv  = rsqrtf(var + 1e-5f);
    float* q  = out + (size_t)bc * HW;
    float* q2 = DUAL ? (out2 + (size_t)bc * HW) : nullptr;
    for (int i = threadIdx.x; i < HW; i += 256) {
        float v = (p[i] - mean) * inv;
        if (RELU) v = fmaxf(v, 0.f);
        if (ADDIN) {
            q[i] = q[i] + v;
        } else {
            q[i] = v;
            if (DUAL) q2[i] = v;
        }
    }
}

extern "C" void kernel_launch(void* const* d_in, const int* in_sizes, int n_in,
                              void* d_out, int out_size, void* d_ws, size_t ws_size,
                              hipStream_t stream)
{
    const float* x      = (const float*)d_in[0];
    const float* w_off1 = (const float*)d_in[1];
    const float* b_off1 = (const float*)d_in[2];
    const float* w1     = (const float*)d_in[3];
    const float* b1     = (const float*)d_in[4];
    const float* w_off2 = (const float*)d_in[5];
    const float* b_off2 = (const float*)d_in[6];
    const float* w2     = (const float*)d_in[7];
    const float* b2     = (const float*)d_in[8];
    const float* w_off3 = (const float*)d_in[9];
    const float* b_off3 = (const float*)d_in[10];
    const float* w3     = (const float*)d_in[11];
    const float* b3     = (const float*)d_in[12];
    const float* rwa[2] = {(const float*)d_in[13], (const float*)d_in[17]};
    const float* rba[2] = {(const float*)d_in[14], (const float*)d_in[18]};
    const float* rwb[2] = {(const float*)d_in[15], (const float*)d_in[19]};
    const float* rbb[2] = {(const float*)d_in[16], (const float*)d_in[20]};

    float* out   = (float*)d_out;
    float* h_out = out;                         // [16,256,32,32]
    float* skip2 = out + 4194304;               // [16,128,64,64]
    float* skip3 = out + 4194304 + 8388608;     // [16,256,32,32]

    // workspace layout (floats). om1 (stage-1, 4-batch chunks) aliases the later pool.
    float* wsf  = (float*)d_ws;
    float* h1   = wsf;                      // 16,777,216  [16,64,128,128]
    float* pool = h1 + 16777216;
    float* om2  = pool;                     // 3,145,728   [16,48,64,64]
    float* om3  = om2 + 3145728;            //   786,432   [16,48,32,32]
    float* y1   = om3 + 786432;             // 4,194,304   [16,256,32,32]
    float* y2   = y1 + 4194304;             // 4,194,304
    float* om1  = pool;                     // 9,633,792 per 4-batch chunk (dead before stage 2)

    // ---- Stage 1: 7x7 s1 p3, Cin=3 -> 64ch @128x128 (4-batch chunks to bound om1)
    for (int c = 0; c < 4; ++c) {
        const float* xc = x + (size_t)c * 4 * 3 * 16384;
        conv_mfma<3,7,7,1,3,128,128,128,128,0><<<dim3(256, 3, 4), 256, 0, stream>>>(
            w_off1, xc, nullptr, b_off1, om1, 147);
        conv_mfma<3,7,7,1,3,128,128,128,128,2><<<dim3(256, 1, 4), 256, 0, stream>>>(
            w1, xc, om1, b1, h1 + (size_t)c * 4 * 64 * 16384, 64);
    }
    instnorm_k<true,false,false><<<16 * 64, 256, 0, stream>>>(h1, h1, nullptr, 16384);

    // ---- Stage 2: 4x4 s2 p1, 64 -> 128ch @64x64
    conv_mfma<64,4,4,2,1,128,128,64,64,0><<<dim3(64, 1, 16), 256, 0, stream>>>(
        w_off2, h1, nullptr, b_off2, om2, 48);
    conv_mfma<64,4,4,2,1,128,128,64,64,2><<<dim3(64, 2, 16), 256, 0, stream>>>(
        w2, h1, om2, b2, skip2, 128);
    instnorm_k<true,false,false><<<16 * 128, 256, 0, stream>>>(skip2, skip2, nullptr, 4096);

    // ---- Stage 3: 4x4 s2 p1, 128 -> 256ch @32x32
    conv_mfma<128,4,4,2,1,64,64,32,32,0><<<dim3(16, 1, 16), 256, 0, stream>>>(
        w_off3, skip2, nullptr, b_off3, om3, 48);
    conv_mfma<128,4,4,2,1,64,64,32,32,2><<<dim3(16, 4, 16), 256, 0, stream>>>(
        w3, skip2, om3, b3, skip3, 256);
    instnorm_k<true,true,false><<<16 * 256, 256, 0, stream>>>(skip3, skip3, h_out, 1024);

    // ---- Residual blocks: reflect-pad 3x3, 256 -> 256 @32x32
    for (int r = 0; r < 2; ++r) {
        conv_mfma<256,3,3,1,1,32,32,32,32,1><<<dim3(16, 4, 16), 256, 0, stream>>>(
            rwa[r], h_out, nullptr, rba[r], y1, 256);
        instnorm_k<true,false,false><<<16 * 256, 256, 0, stream>>>(y1, y1, nullptr, 1024);
        conv_mfma<256,3,3,1,1,32,32,32,32,1><<<dim3(16, 4, 16), 256, 0, stream>>>(
            rwb[r], y1, nullptr, rbb[r], y2, 256);
        instnorm_k<false,false,true><<<16 * 256, 256, 0, stream>>>(y2, h_out, nullptr, 1024);
    }
}

// Round 8
// 1505.303 us; speedup vs baseline: 3.0736x; 1.1886x over previous
//
#include <hip/hip_runtime.h>
#include <math.h>

typedef __attribute__((ext_vector_type(8))) short short8;
typedef __attribute__((ext_vector_type(4))) float floatx4;
typedef __attribute__((ext_vector_type(4))) _Float16 half4;

__device__ __forceinline__ unsigned short f2bf(float f) {
    unsigned u = __builtin_bit_cast(unsigned, f);
    u += 0x7FFFu + ((u >> 16) & 1u);   // RNE
    return (unsigned short)(u >> 16);
}

// Implicit-GEMM conv on bf16 MFMA: Out[z][m][n] = sum_k A[m][k]*B(k,n) + bias[m]
// MODE 0: zero-pad im2col  MODE 1: reflect-pad im2col  MODE 2: deform bilinear*sigmoid(mask)
// Tile: BM=64*MT, BN=64, BK=64. 256 threads = 4 waves.
// MT (m-tiles per block) amortizes the expensive sampled B-tile over more
// output channels. NOTE: grid.y must be ceil(M / (64*MT)) — R6 regression was
// launching the M=147 off-conv with one 128-row block (channels 128..146 poison).
// B-stage is n-major: lane = n, so gathers for a fixed (ci,r) are consecutive
// across lanes (line-shared). Deform meta is a packed base index (independently
// clamped corners + step bits) + mask-premultiplied half4 weights:
//   packed = (yc0*W+xc0) | (xc1-xc0)<<24 | (yc1-yc0)<<25
// Corner addrs base, base+dx, base+dy*W, base+dy*W+dx are the EXACT clamped
// corners for every in/out-of-bounds combination (OOB corners carry weight 0).
template<int CIN,int KH,int KW,int STR,int PAD,int H,int W,int HO,int WO,int MODE,int MT>
__global__ __launch_bounds__(256) void conv_mfma(
    const float* __restrict__ A,      // [M x Ktot] weights (OIHW flat)
    const float* __restrict__ X,      // [Z][CIN][H][W]
    const float* __restrict__ OM,     // [Z][3*Kk][HO][WO] (deform only)
    const float* __restrict__ bias,   // [M]
    float* __restrict__ Out,          // [Z][M][HO*WO]
    int M)
{
    constexpr int Kk   = KH*KW;
    constexpr int Ktot = CIN*Kk;
    constexpr int HWc  = H*W;
    constexpr int HOWO = HO*WO;
    constexpr int KT   = (Ktot + 63) & ~63;
    constexpr bool FASTA  = (Ktot % 64 == 0);
    constexpr bool KGUARD = (Ktot % 64 != 0);
    constexpr bool META2  = (MODE == 2) && (Kk == 16);   // deform packed meta
    constexpr bool META01 = (MODE != 2);                 // gather-idx meta
    constexpr int KPAD = (Kk % 2 == 0) ? Kk + 1 : Kk;    // bank-friendly stride

    const int z = blockIdx.z;
    const float* __restrict__ Xb  = X + (size_t)z * CIN * HWc;
    const float* __restrict__ OMb = (MODE == 2) ? (OM + (size_t)z * 3 * Kk * HOWO) : nullptr;
    float* __restrict__ Outb = Out + (size_t)z * (size_t)M * HOWO;

    const int n0   = blockIdx.x * 64;
    const int m0   = blockIdx.y * (64 * MT);
    const int tid  = threadIdx.x;
    const int lane = tid & 63;
    const int wave = tid >> 6;
    const int quad = lane >> 4;
    const int l16  = lane & 15;

    __shared__ unsigned short As[64 * MT][64];
    __shared__ unsigned short Bs[64][64];
    __shared__ int   MIb[META2 ? 64 * KPAD : 1];
    __shared__ half4 MWh[META2 ? 64 * KPAD : 1];
    __shared__ int   MI0[META01 ? 64 * KPAD : 1];

    // ---- precompute sampling metadata for the block's 64 n's x Kk taps
    if constexpr (META2) {
        for (int e = tid; e < 64 * Kk; e += 256) {
            int n = e / Kk, r = e - n * Kk;
            int gn = n0 + n, ho = gn / WO, wo = gn % WO;
            int ky = r / KW, kx = r % KW;
            float offy = OMb[(size_t)(2 * r) * HOWO + gn];
            float offx = OMb[(size_t)(2 * r + 1) * HOWO + gn];
            float ml   = OMb[(size_t)(2 * Kk + r) * HOWO + gn];
            float mask = 1.f / (1.f + expf(-ml));
            float ys = (float)(ho * STR - PAD + ky) + offy;
            float xs = (float)(wo * STR - PAD + kx) + offx;
            float y0f = floorf(ys), x0f = floorf(xs);
            float dy = ys - y0f, dx = xs - x0f;
            int y0 = (int)y0f, x0 = (int)x0f;
            int yc0 = min(max(y0, 0), H - 1);
            int yc1 = min(max(y0 + 1, 0), H - 1);
            int xc0 = min(max(x0, 0), W - 1);
            int xc1 = min(max(x0 + 1, 0), W - 1);
            bool y0ok = (y0 >= 0) & (y0 < H), y1ok = (y0 + 1 >= 0) & (y0 + 1 < H);
            bool x0ok = (x0 >= 0) & (x0 < W), x1ok = (x0 + 1 >= 0) & (x0 + 1 < W);
            half4 w;
            w[0] = (_Float16)((y0ok && x0ok) ? (1.f - dy) * (1.f - dx) * mask : 0.f);
            w[1] = (_Float16)((y0ok && x1ok) ? (1.f - dy) * dx * mask : 0.f);
            w[2] = (_Float16)((y1ok && x0ok) ? dy * (1.f - dx) * mask : 0.f);
            w[3] = (_Float16)((y1ok && x1ok) ? dy * dx * mask : 0.f);
            MIb[n * KPAD + r] = (yc0 * W + xc0) | ((xc1 - xc0) << 24) | ((yc1 - yc0) << 25);
            MWh[n * KPAD + r] = w;
        }
        __syncthreads();
    }
    if constexpr (META01) {
        for (int e = tid; e < 64 * Kk; e += 256) {
            int n = e / Kk, r = e - n * Kk;
            int gn = n0 + n, ho = gn / WO, wo = gn % WO;
            int ky = r / KW, kx = r % KW;
            int idx;
            if constexpr (MODE == 0) {
                int iy = ho * STR - PAD + ky;
                int ix = wo * STR - PAD + kx;
                idx = (iy >= 0 && iy < H && ix >= 0 && ix < W) ? iy * W + ix : -1;
            } else {
                int iy = ho - PAD + ky; iy = iy < 0 ? -iy : (iy >= H ? 2 * H - 2 - iy : iy);
                int ix = wo - PAD + kx; ix = ix < 0 ? -ix : (ix >= W ? 2 * W - 2 - ix : ix);
                idx = iy * W + ix;
            }
            MI0[n * KPAD + r] = idx;
        }
        __syncthreads();
    }

    floatx4 acc[MT][4];
#pragma unroll
    for (int s = 0; s < MT; ++s)
#pragma unroll
        for (int t = 0; t < 4; ++t) acc[s][t] = (floatx4){0.f, 0.f, 0.f, 0.f};

    // staging maps
    const int am  = tid >> 2;   // A: row within 64-strip
    const int akc = tid & 3;    // A: 16-float chunk
    const int bn2 = tid & 63;   // B: n (lane) -> coalesced gathers
    const int bkc = tid >> 6;   // B: 16-k chunk (0..3)
    const int gn2 = n0 + bn2;
    const int ho2 = gn2 / WO, wo2 = gn2 % WO;

    for (int k0 = 0; k0 < KT; k0 += 64) {
        // ---- stage A tile(s) (fp32 global -> bf16 LDS)
#pragma unroll
        for (int s = 0; s < MT; ++s) {
            const int row = s * 64 + am;
            const int gm = m0 + row;
            unsigned short tmp[16];
            if constexpr (FASTA) {
                if (gm < M) {
                    const float4* p = (const float4*)(A + (size_t)gm * Ktot + k0 + akc * 16);
                    float4 f0 = p[0], f1 = p[1], f2 = p[2], f3 = p[3];
                    tmp[0]=f2bf(f0.x); tmp[1]=f2bf(f0.y); tmp[2]=f2bf(f0.z); tmp[3]=f2bf(f0.w);
                    tmp[4]=f2bf(f1.x); tmp[5]=f2bf(f1.y); tmp[6]=f2bf(f1.z); tmp[7]=f2bf(f1.w);
                    tmp[8]=f2bf(f2.x); tmp[9]=f2bf(f2.y); tmp[10]=f2bf(f2.z); tmp[11]=f2bf(f2.w);
                    tmp[12]=f2bf(f3.x); tmp[13]=f2bf(f3.y); tmp[14]=f2bf(f3.z); tmp[15]=f2bf(f3.w);
                } else {
#pragma unroll
                    for (int j = 0; j < 16; ++j) tmp[j] = 0;
                }
            } else {
#pragma unroll
                for (int j = 0; j < 16; ++j) {
                    int gk = k0 + akc * 16 + j;
                    float v = (gm < M && gk < Ktot) ? A[(size_t)gm * Ktot + gk] : 0.f;
                    tmp[j] = f2bf(v);
                }
            }
            short8 s0, s1;
#pragma unroll
            for (int j = 0; j < 8; ++j) { s0[j] = (short)tmp[j]; s1[j] = (short)tmp[8 + j]; }
            const int g0 = (akc * 2)     ^ (am & 7);
            const int g1 = (akc * 2 + 1) ^ (am & 7);
            *(short8*)&As[row][g0 * 8] = s0;
            *(short8*)&As[row][g1 * 8] = s1;
        }

        // ---- stage B tile (sampled -> bf16 LDS), n-major
        {
            unsigned short tmp[16];
            if constexpr (META2) {
                // Kk==16: ci fixed for this thread's 16-k chunk
                const int ci = (k0 >> 4) + bkc;
                const float* img = Xb + (size_t)ci * HWc;
#pragma unroll
                for (int j = 0; j < 16; ++j) {
                    int packed = MIb[bn2 * KPAD + j];
                    half4 w    = MWh[bn2 * KPAD + j];
                    int base = packed & 0xFFFFFF;
                    int dxs  = (packed >> 24) & 1;
                    int dys  = ((packed >> 25) & 1) ? W : 0;
                    float v = (float)w[0] * img[base]
                            + (float)w[1] * img[base + dxs]
                            + (float)w[2] * img[base + dys]
                            + (float)w[3] * img[base + dys + dxs];
                    tmp[j] = f2bf(v);
                }
            } else if constexpr (META01) {
#pragma unroll
                for (int j = 0; j < 16; ++j) {
                    int gk = k0 + bkc * 16 + j;
                    float v = 0.f;
                    if (!KGUARD || gk < Ktot) {
                        int ci, r;
                        if constexpr (Kk == 16) { ci = gk >> 4; r = gk & 15; }
                        else { ci = gk / Kk; r = gk - ci * Kk; }
                        int idx = MI0[bn2 * KPAD + r];
                        if (MODE == 1 || idx >= 0)
                            v = Xb[(size_t)ci * HWc + idx];
                    }
                    tmp[j] = f2bf(v);
                }
            } else {
                // direct deform path (stage 1: Kk=49, meta too large for LDS)
#pragma unroll 4
                for (int j = 0; j < 16; ++j) {
                    int gk = k0 + bkc * 16 + j;
                    float v = 0.f;
                    if (!KGUARD || gk < Ktot) {
                        int ci = gk / Kk;
                        int r  = gk - ci * Kk;
                        int ky = r / KW, kx = r % KW;
                        const float* img = Xb + (size_t)ci * HWc;
                        float offy = OMb[(size_t)(2 * r) * HOWO + gn2];
                        float offx = OMb[(size_t)(2 * r + 1) * HOWO + gn2];
                        float ml   = OMb[(size_t)(2 * Kk + r) * HOWO + gn2];
                        float mask = 1.f / (1.f + expf(-ml));
                        float ys = (float)(ho2 * STR - PAD + ky) + offy;
                        float xs = (float)(wo2 * STR - PAD + kx) + offx;
                        float y0f = floorf(ys), x0f = floorf(xs);
                        float dy = ys - y0f, dx = xs - x0f;
                        int y0 = (int)y0f, x0 = (int)x0f;
                        float v00 = 0.f, v01 = 0.f, v10 = 0.f, v11 = 0.f;
                        bool y0ok = (y0 >= 0) & (y0 < H), y1ok = (y0 + 1 >= 0) & (y0 + 1 < H);
                        bool x0ok = (x0 >= 0) & (x0 < W), x1ok = (x0 + 1 >= 0) & (x0 + 1 < W);
                        if (y0ok && x0ok) v00 = img[y0 * W + x0];
                        if (y0ok && x1ok) v01 = img[y0 * W + x0 + 1];
                        if (y1ok && x0ok) v10 = img[(y0 + 1) * W + x0];
                        if (y1ok && x1ok) v11 = img[(y0 + 1) * W + x0 + 1];
                        v = (v00 * (1.f - dy) * (1.f - dx) + v01 * (1.f - dy) * dx +
                             v10 * dy * (1.f - dx) + v11 * dy * dx) * mask;
                    }
                    tmp[j] = f2bf(v);
                }
            }
            short8 s0, s1;
#pragma unroll
            for (int j = 0; j < 8; ++j) { s0[j] = (short)tmp[j]; s1[j] = (short)tmp[8 + j]; }
            const int g0 = (bkc * 2)     ^ (bn2 & 7);
            const int g1 = (bkc * 2 + 1) ^ (bn2 & 7);
            *(short8*)&Bs[bn2][g0 * 8] = s0;
            *(short8*)&Bs[bn2][g1 * 8] = s1;
        }
        __syncthreads();

        // ---- MFMA: wave computes MT x 16(m) x 64(n), K=64
        {
            const int mrow = wave * 16 + l16;
#pragma unroll
            for (int kk = 0; kk < 2; ++kk) {
                const int kg = kk * 4 + quad;
                short8 a[MT];
#pragma unroll
                for (int s = 0; s < MT; ++s)
                    a[s] = *(const short8*)&As[s * 64 + mrow][((kg ^ (mrow & 7)) * 8)];
#pragma unroll
                for (int t = 0; t < 4; ++t) {
                    const int ncol = t * 16 + l16;
                    short8 b = *(const short8*)&Bs[ncol][((kg ^ (ncol & 7)) * 8)];
#pragma unroll
                    for (int s = 0; s < MT; ++s)
                        acc[s][t] = __builtin_amdgcn_mfma_f32_16x16x32_bf16(a[s], b, acc[s][t], 0, 0, 0);
                }
            }
        }
        __syncthreads();
    }

    // ---- epilogue: bias + store. D layout: row = quad*4+i, col = lane&15
#pragma unroll
    for (int s = 0; s < MT; ++s) {
#pragma unroll
        for (int t = 0; t < 4; ++t) {
            const int ng = n0 + t * 16 + l16;
#pragma unroll
            for (int i = 0; i < 4; ++i) {
                int mg = m0 + s * 64 + wave * 16 + quad * 4 + i;
                if (mg < M)
                    Outb[(size_t)mg * HOWO + ng] = acc[s][t][i] + bias[mg];
            }
        }
    }
}

// Instance norm over HW per (b,c) block; optional ReLU, dual-write, add-into-out.
template<bool RELU, bool DUAL, bool ADDIN>
__global__ __launch_bounds__(256) void instnorm_k(
    const float* __restrict__ in, float* __restrict__ out,
    float* __restrict__ out2, int HW)
{
    const int bc = blockIdx.x;
    const float* p = in + (size_t)bc * HW;
    float s = 0.f, ss = 0.f;
    for (int i = threadIdx.x; i < HW; i += 256) { float v = p[i]; s += v; ss += v * v; }
    __shared__ float rs[256], rq[256];
    rs[threadIdx.x] = s; rq[threadIdx.x] = ss;
    __syncthreads();
    for (int o = 128; o > 0; o >>= 1) {
        if (threadIdx.x < o) { rs[threadIdx.x] += rs[threadIdx.x + o]; rq[threadIdx.x] += rq[threadIdx.x + o]; }
        __syncthreads();
    }
    float mean = rs[0] / (float)HW;
    float var  = rq[0] / (float)HW - mean * mean;
    float inv  = rsqrtf(var + 1e-5f);
    float* q  = out + (size_t)bc * HW;
    float* q2 = DUAL ? (out2 + (size_t)bc * HW) : nullptr;
    for (int i = threadIdx.x; i < HW; i += 256) {
        float v = (p[i] - mean) * inv;
        if (RELU) v = fmaxf(v, 0.f);
        if (ADDIN) {
            q[i] = q[i] + v;
        } else {
            q[i] = v;
            if (DUAL) q2[i] = v;
        }
    }
}

extern "C" void kernel_launch(void* const* d_in, const int* in_sizes, int n_in,
                              void* d_out, int out_size, void* d_ws, size_t ws_size,
                              hipStream_t stream)
{
    const float* x      = (const float*)d_in[0];
    const float* w_off1 = (const float*)d_in[1];
    const float* b_off1 = (const float*)d_in[2];
    const float* w1     = (const float*)d_in[3];
    const float* b1     = (const float*)d_in[4];
    const float* w_off2 = (const float*)d_in[5];
    const float* b_off2 = (const float*)d_in[6];
    const float* w2     = (const float*)d_in[7];
    const float* b2     = (const float*)d_in[8];
    const float* w_off3 = (const float*)d_in[9];
    const float* b_off3 = (const float*)d_in[10];
    const float* w3     = (const float*)d_in[11];
    const float* b3     = (const float*)d_in[12];
    const float* rwa[2] = {(const float*)d_in[13], (const float*)d_in[17]};
    const float* rba[2] = {(const float*)d_in[14], (const float*)d_in[18]};
    const float* rwb[2] = {(const float*)d_in[15], (const float*)d_in[19]};
    const float* rbb[2] = {(const float*)d_in[16], (const float*)d_in[20]};

    float* out   = (float*)d_out;
    float* h_out = out;                         // [16,256,32,32]
    float* skip2 = out + 4194304;               // [16,128,64,64]
    float* skip3 = out + 4194304 + 8388608;     // [16,256,32,32]

    // workspace layout (floats). om1 (stage-1, 4-batch chunks) aliases the later pool.
    float* wsf  = (float*)d_ws;
    float* h1   = wsf;                      // 16,777,216  [16,64,128,128]
    float* pool = h1 + 16777216;
    float* om2  = pool;                     // 3,145,728   [16,48,64,64]
    float* om3  = om2 + 3145728;            //   786,432   [16,48,32,32]
    float* y1   = om3 + 786432;             // 4,194,304   [16,256,32,32]
    float* y2   = y1 + 4194304;             // 4,194,304
    float* om1  = pool;                     // 9,633,792 per 4-batch chunk (dead before stage 2)

    // ---- Stage 1: 7x7 s1 p3, Cin=3 -> 64ch @128x128 (4-batch chunks to bound om1)
    for (int c = 0; c < 4; ++c) {
        const float* xc = x + (size_t)c * 4 * 3 * 16384;
        conv_mfma<3,7,7,1,3,128,128,128,128,0,2><<<dim3(256, 2, 4), 256, 0, stream>>>(
            w_off1, xc, nullptr, b_off1, om1, 147);
        conv_mfma<3,7,7,1,3,128,128,128,128,2,1><<<dim3(256, 1, 4), 256, 0, stream>>>(
            w1, xc, om1, b1, h1 + (size_t)c * 4 * 64 * 16384, 64);
    }
    instnorm_k<true,false,false><<<16 * 64, 256, 0, stream>>>(h1, h1, nullptr, 16384);

    // ---- Stage 2: 4x4 s2 p1, 64 -> 128ch @64x64
    conv_mfma<64,4,4,2,1,128,128,64,64,0,1><<<dim3(64, 1, 16), 256, 0, stream>>>(
        w_off2, h1, nullptr, b_off2, om2, 48);
    conv_mfma<64,4,4,2,1,128,128,64,64,2,2><<<dim3(64, 1, 16), 256, 0, stream>>>(
        w2, h1, om2, b2, skip2, 128);
    instnorm_k<true,false,false><<<16 * 128, 256, 0, stream>>>(skip2, skip2, nullptr, 4096);

    // ---- Stage 3: 4x4 s2 p1, 128 -> 256ch @32x32
    conv_mfma<128,4,4,2,1,64,64,32,32,0,1><<<dim3(16, 1, 16), 256, 0, stream>>>(
        w_off3, skip2, nullptr, b_off3, om3, 48);
    conv_mfma<128,4,4,2,1,64,64,32,32,2,2><<<dim3(16, 2, 16), 256, 0, stream>>>(
        w3, skip2, om3, b3, skip3, 256);
    instnorm_k<true,true,false><<<16 * 256, 256, 0, stream>>>(skip3, skip3, h_out, 1024);

    // ---- Residual blocks: reflect-pad 3x3, 256 -> 256 @32x32
    for (int r = 0; r < 2; ++r) {
        conv_mfma<256,3,3,1,1,32,32,32,32,1,2><<<dim3(16, 2, 16), 256, 0, stream>>>(
            rwa[r], h_out, nullptr, rba[r], y1, 256);
        instnorm_k<true,false,false><<<16 * 256, 256, 0, stream>>>(y1, y1, nullptr, 1024);
        conv_mfma<256,3,3,1,1,32,32,32,32,1,2><<<dim3(16, 2, 16), 256, 0, stream>>>(
            rwb[r], y1, nullptr, rbb[r], y2, 256);
        instnorm_k<false,false,true><<<16 * 256, 256, 0, stream>>>(y2, h_out, nullptr, 1024);
    }
}